// Round 8
// baseline (89.740 us; speedup 1.0000x reference)
//
#include <hip/hip_runtime.h>

// PointWarping2 = flash-attention with head-dim 3:
//   flow2 = softmax(-d2/s^2) @ f1  (Schraudolph exp2 in f16-bit domain).
// R25 = R24's math, ONE kernel. R24 was null vs R23 (-23% VALU -> 0),
// proving main is no longer issue-bound (~6.5us incl ramp); the remaining
// controllable cost is the pack dispatch + pack->main boundary (~5us).
// Structure: grid 256 (1 block/CU, provably co-resident at
// __launch_bounds__(1024,4)); each block packs 64 srcA + 32 fpk records
// (no redundancy -- R20's mistake avoided), then a device-scope software
// grid barrier (threadfence -> atomicAdd -> relaxed-agent spin ->
// threadfence), then R24's main loop unchanged. Query B-frags computed
// BEFORE the spin so xyz2 latency hides under the barrier wait.
// Counter at ws offset 0, zeroed by capture-legal hipMemsetAsync.
//
// Score MFMA 32x32x8_f16: D[src][q] = A.B + 0
//   A (per source): k0-3 {yx,yy,yz,1} (lanes<32), k4-7 {1,wh,wl,0}
//     (w = -c1*|y|^2 fp32 -> f16 hi/lo; coords single f16)
//   B (per query):  k0-3 {X,Y,Z,qch}, k4-7 {qcl,1,1,0}
//     (X = 2c1*qx f16; qc = 30 - c1*|q|^2 f16 hi/lo)
//   => D = 30 - c1*d2 = 30 + log2(weight); packed-f16 Schraudolph:
//   per score-pair: cvt_pkrtz -> v_pk_max_f16(16) -> v_pk_mad_u16(*16+0x43D4)
//   -- the result IS the PV B-word.
// PV MFMA 32x32x16_f16: D layout (col=lane&31=q,
// row=(reg&3)+8*(reg>>2)+4*hi=src) => packed weights are the PV B-operand
// when flow values are stored permuted {0-3,8-11 | 4-7,12-15} per
// 16-source group (fpk). acc regs 0-3 on lanes<32 = (nx,ny,nz,den)/query.

#define N1S  8192
#define N2S  8192
#define BATCH 2
#define NS   (BATCH * N1S)       // 16384 sources
#define NQ   (BATCH * N2S)       // 16384 queries
#define GA   (NS + 128)          // srcA records + guard
#define NF   (NS/2 + 64)         // fpk records + guard
#define BLK  1024                // 16 waves; each wave: 512 sources = 16 tiles
#define QBQ  64                  // queries per block (2 cols of 32)
#define NBLK (NQ / QBQ)          // 256 blocks = 1 per CU
#define LOG2E 1.4426950408889634f
#define BIAS 30.0f               // s = BIAS + log2(w); s in [16, ~30.1]
#define ONEH 0x3C00u             // f16(1.0)
#define WADJ 0x43D4u             // 0x4400 base - 44 Schraudolph mid-corr

typedef __attribute__((ext_vector_type(2)))  __fp16         hp2;
typedef __attribute__((ext_vector_type(4)))  _Float16 f16x4;
typedef __attribute__((ext_vector_type(8)))  _Float16 f16x8;
typedef __attribute__((ext_vector_type(16))) float    f32x16;

__device__ __forceinline__ float read_scale(const void* p) {
    // resol_factor: 1-elem array; Python int -> int32, float -> fp32.
    int iv = *(const int*)p;
    if (iv > -(1 << 23) && iv < (1 << 23)) return (float)iv;
    return *(const float*)p;
}

__device__ __forceinline__ unsigned hb(float v) {        // f16 bits, RNE
    return (unsigned)__builtin_bit_cast(unsigned short, (_Float16)v);
}
__device__ __forceinline__ float h2f(unsigned b16) {     // f16 bits -> fp32
    return (float)__builtin_bit_cast(_Float16, (unsigned short)(b16 & 0xFFFFu));
}

// two Schraudolph-f16 weights from two f32 scores: one packed PV B-word.
// 3 VALU: v_cvt_pkrtz_f16_f32, v_pk_max_f16, v_pk_mad_u16.
__device__ __forceinline__ unsigned wpair(float a, float b,
                                          unsigned mul16, unsigned adj) {
    hp2 s = __builtin_amdgcn_cvt_pkrtz(a, b);            // v_cvt_pkrtz_f16_f32
    const hp2 cl = {(__fp16)16.0f, (__fp16)16.0f};
    s = __builtin_elementwise_max(s, cl);                // v_pk_max_f16
    unsigned u = __builtin_bit_cast(unsigned, s), r;
    asm("v_pk_mad_u16 %0, %1, %2, %3"
        : "=v"(r) : "v"(u), "v"(mul16), "v"(adj));
    return r;
}

// ---- fused kernel: pack 1/256th -> grid barrier -> main ----
__global__ __launch_bounds__(BLK, 4) void pw2_fused(
    const float* __restrict__ xyz1, const float* __restrict__ xyz2,
    const float* __restrict__ flow1, const void* __restrict__ resol,
    uint4* __restrict__ srcA, uint4* __restrict__ fpk,
    unsigned* __restrict__ cnt, float* __restrict__ out)
{
    __shared__ float4 red[16][QBQ];   // [wave][query] partial (nx,ny,nz,den)

    const int t  = threadIdx.x;
    const int w  = t >> 6, l = t & 63, lq = l & 31, hi = l >> 5;
    const int qblk  = blockIdx.x * QBQ;
    const int b     = qblk >> 13;
    const int nbase = qblk & (N2S - 1);

    const float scale = read_scale(resol);
    const float c1 = LOG2E / (scale * scale), twoC = 2.0f * c1;
    const float* x2b = xyz2 + b * 3 * N2S;

    // ================= phase 1: pack this block's share =================
    if (t < 64) {
        const int i = blockIdx.x * 64 + t;          // srcA record
        const int bb = i >> 13, m = i & (N1S - 1);
        const float* x1b = xyz1  + bb * 3 * N1S;
        const float* f1b = flow1 + bb * 3 * N1S;
        float fx = f1b[0*N1S+m], fy = f1b[1*N1S+m], fz = f1b[2*N1S+m];
        float yx = x1b[0*N1S+m]+fx, yy = x1b[1*N1S+m]+fy, yz = x1b[2*N1S+m]+fz;
        float wq = -c1 * (yx*yx + yy*yy + yz*yz);   // fp32-exact, f16 hi/lo
        unsigned hx = hb(yx), hy = hb(yy), hz = hb(yz);
        unsigned wh = hb(wq), wl = hb(wq - h2f(wh));
        uint4 A;                      // halves: lanes<32 read .xy, >=32 .zw
        A.x = hx | (hy << 16);        // k0,k1 = yx,yy
        A.y = hz | (ONEH << 16);      // k2,k3 = yz,1
        A.z = ONEH | (wh << 16);      // k4,k5 = 1,wh
        A.w = wl;                     // k6,k7 = wl,0
        srcA[i] = A;
    } else if (t < 96) {
        const int i = blockIdx.x * 32 + (t - 64);   // fpk record
        // record i: group g of 16 sources, half h, component c (c=3 -> 1).
        // k-order permutation: h=0 -> {0,1,2,3,8,9,10,11},
        //                      h=1 -> {4,5,6,7,12,13,14,15}.
        const int g = i >> 3, h = (i >> 2) & 1, c = i & 3;
        const int bb = g >> 9, m0 = (g & 511) * 16;
        const float* f1c = flow1 + bb * 3 * N1S + (c < 3 ? c : 0) * N1S;
        const int base = h * 4;
        unsigned e[8];
#pragma unroll
        for (int j = 0; j < 8; ++j) {
            int s = m0 + base + (j & 3) + (j >> 2) * 8;
            e[j] = (c == 3) ? ONEH : hb(f1c[s]);
        }
        uint4 F;
        F.x = e[0] | (e[1] << 16);
        F.y = e[2] | (e[3] << 16);
        F.z = e[4] | (e[5] << 16);
        F.w = e[6] | (e[7] << 16);
        fpk[i] = F;
    }

    // ---- per-lane query constants (input arrays; safe pre-barrier) ----
    const unsigned mul16 = 0x00100010u;
    const unsigned adj   = (WADJ << 16) | WADJ;
    uint2 bw0, bw1;
#pragma unroll
    for (int cc = 0; cc < 2; ++cc) {
        const int n0 = nbase + 32 * cc + lq;
        const float qx = x2b[n0], qy = x2b[N2S+n0], qz = x2b[2*N2S+n0];
        const unsigned Xh = hb(twoC*qx), Yh = hb(twoC*qy), Zh = hb(twoC*qz);
        const float qc = BIAS - c1 * (qx*qx + qy*qy + qz*qz);
        const unsigned Qh = hb(qc), Ql = hb(qc - h2f(Qh));
        uint2 bwv;
        bwv.x = hi ? (Ql | (ONEH << 16)) : (Xh | (Yh << 16)); // k4,k5 | k0,k1
        bwv.y = hi ? ONEH                : (Zh | (Qh << 16)); // k6,k7 | k2,k3
        if (cc == 0) bw0 = bwv; else bw1 = bwv;
    }
    const f16x4 Bf0 = __builtin_bit_cast(f16x4, bw0);
    const f16x4 Bf1 = __builtin_bit_cast(f16x4, bw1);

    // ================= grid barrier (device scope) =================
    __syncthreads();                  // block's pack writes issued & complete
    if (t == 0) {
        __threadfence();              // release: flush L2 (agent fence)
        atomicAdd(cnt, 1u);           // device-scope RMW
        unsigned spins = 0;
        while (__hip_atomic_load(cnt, __ATOMIC_RELAXED,
                                 __HIP_MEMORY_SCOPE_AGENT) < (unsigned)NBLK) {
            __builtin_amdgcn_s_sleep(2);
            if (++spins > (1u << 22)) break;   // failsafe: no hang
        }
        __threadfence();              // acquire: invalidate stale L2 lines
    }
    __syncthreads();

    // ================= phase 2: main (identical to R24) =================
    f32x16 acc0, acc1, zc;
#pragma unroll
    for (int k = 0; k < 16; ++k) { acc0[k] = 0.f; acc1[k] = 0.f; zc[k] = 0.f; }

    const uint2* a2 = (const uint2*)srcA;   // lane reads its 8B half-record
    int ia = (b * N1S + w * 512 + lq) * 2 + hi;
    int ir = ((b * N1S + w * 512) >> 4) * 8 + hi * 4 + (l & 3);

    uint2 s0 = a2[ia];
    uint4 f0 = fpk[ir], f1 = fpk[ir + 8];

#pragma unroll 2
    for (int tt = 0; tt < 16; ++tt) {
        // prefetch next tile (guard regions: always legal)
        const uint2 s0n = a2[ia + 64];
        const uint4 f0n = fpk[ir + 16];
        const uint4 f1n = fpk[ir + 24];

        const f32x16 d0 = __builtin_amdgcn_mfma_f32_32x32x8f16(
            __builtin_bit_cast(f16x4, s0), Bf0, zc, 0, 0, 0);
        const f32x16 d1 = __builtin_amdgcn_mfma_f32_32x32x8f16(
            __builtin_bit_cast(f16x4, s0), Bf1, zc, 0, 0, 0);

        uint4 p;
        p.x = wpair(d0[0],  d0[1],  mul16, adj);
        p.y = wpair(d0[2],  d0[3],  mul16, adj);
        p.z = wpair(d0[4],  d0[5],  mul16, adj);
        p.w = wpair(d0[6],  d0[7],  mul16, adj);
        acc0 = __builtin_amdgcn_mfma_f32_32x32x16_f16(
            __builtin_bit_cast(f16x8, f0), __builtin_bit_cast(f16x8, p),
            acc0, 0, 0, 0);
        p.x = wpair(d0[8],  d0[9],  mul16, adj);
        p.y = wpair(d0[10], d0[11], mul16, adj);
        p.z = wpair(d0[12], d0[13], mul16, adj);
        p.w = wpair(d0[14], d0[15], mul16, adj);
        acc0 = __builtin_amdgcn_mfma_f32_32x32x16_f16(
            __builtin_bit_cast(f16x8, f1), __builtin_bit_cast(f16x8, p),
            acc0, 0, 0, 0);

        p.x = wpair(d1[0],  d1[1],  mul16, adj);
        p.y = wpair(d1[2],  d1[3],  mul16, adj);
        p.z = wpair(d1[4],  d1[5],  mul16, adj);
        p.w = wpair(d1[6],  d1[7],  mul16, adj);
        acc1 = __builtin_amdgcn_mfma_f32_32x32x16_f16(
            __builtin_bit_cast(f16x8, f0), __builtin_bit_cast(f16x8, p),
            acc1, 0, 0, 0);
        p.x = wpair(d1[8],  d1[9],  mul16, adj);
        p.y = wpair(d1[10], d1[11], mul16, adj);
        p.z = wpair(d1[12], d1[13], mul16, adj);
        p.w = wpair(d1[14], d1[15], mul16, adj);
        acc1 = __builtin_amdgcn_mfma_f32_32x32x16_f16(
            __builtin_bit_cast(f16x8, f1), __builtin_bit_cast(f16x8, p),
            acc1, 0, 0, 0);

        s0 = s0n; f0 = f0n; f1 = f1n;
        ia += 64; ir += 16;
    }

    // ---- cross-wave reduce + normalize + write ----
    if (hi == 0) {
        red[w][lq]      = make_float4(acc0[0], acc0[1], acc0[2], acc0[3]);
        red[w][32 + lq] = make_float4(acc1[0], acc1[1], acc1[2], acc1[3]);
    }
    __syncthreads();
    if (t < QBQ) {
        float nx = 0.f, ny = 0.f, nz = 0.f, dn = 0.f;
#pragma unroll
        for (int ww = 0; ww < 16; ++ww) {
            float4 r = red[ww][t];
            nx += r.x; ny += r.y; nz += r.z; dn += r.w;
        }
        const float inv = 1.0f / dn;
        const int nq = nbase + t;
        out[b*3*N2S + 0*N2S + nq] = x2b[0*N2S+nq] - nx * inv;
        out[b*3*N2S + 1*N2S + nq] = x2b[1*N2S+nq] - ny * inv;
        out[b*3*N2S + 2*N2S + nq] = x2b[2*N2S+nq] - nz * inv;
    }
}

extern "C" void kernel_launch(void* const* d_in, const int* in_sizes, int n_in,
                              void* d_out, int out_size, void* d_ws, size_t ws_size,
                              hipStream_t stream) {
    const float* xyz1  = (const float*)d_in[0];
    const float* xyz2  = (const float*)d_in[1];
    const float* flow1 = (const float*)d_in[2];
    const void*  resol = d_in[3];
    float* out = (float*)d_out;

    unsigned* cnt = (unsigned*)d_ws;               // barrier counter @ 0
    uint4* srcA = (uint4*)((char*)d_ws + 256);     // GA records
    uint4* fpk  = srcA + GA;                       // NF records; ~400 KB

    hipMemsetAsync(cnt, 0, sizeof(unsigned), stream);   // ws is re-poisoned
    pw2_fused<<<NBLK, BLK, 0, stream>>>(xyz1, xyz2, flow1, resol,
                                        srcA, fpk, cnt, out);
}

// Round 9
// 73.692 us; speedup vs baseline: 1.2178x; 1.2178x over previous
//
#include <hip/hip_runtime.h>

// PointWarping2 = flash-attention with head-dim 3:
//   flow2 = softmax(-d2/s^2) @ f1  (Schraudolph exp2 in f16-bit domain).
// R26 = exact revert to R24 (best measured: 74.0us; R23 tie at 73.9).
// Session evidence closing every branch:
//  - R24 (-23% VALU ops) was NULL -> main not issue-bound.
//  - R19/R21 software pipelining ~null -> not dependency-bound.
//  - R23 occupancy 2->4 waves/SIMD: -6.6us (captured). 8 waves needs
//    <64 VGPR: impossible with 2x f32x16 accumulators.
//  - R20 redundant-pack fusion: +4us. R25 grid-barrier fusion: +16us
//    (straggler wait + 256-block fence/atomic storm). Two-kernel wins.
//  - Harness floor: 40us ws poison fill @ 84% HBM peak + ~22us reset/
//    launch -> ~62us fixed; controllable ~11.5us (pack 2.5 + boundary
//    2.5 + main 6.5, main within ~2x of pure issue floor).
//
// Score MFMA 32x32x8_f16: D[src][q] = A.B + 0
//   A (per source): k0-3 {yx,yy,yz,1} (lanes<32), k4-7 {1,wh,wl,0}
//     (w = -c1*|y|^2 fp32 -> f16 hi/lo; coords single f16)
//   B (per query):  k0-3 {X,Y,Z,qch}, k4-7 {qcl,1,1,0}
//     (X = 2c1*qx f16; qc = 30 - c1*|q|^2 f16 hi/lo)
//   => D = 30 - c1*d2 = 30 + log2(weight); packed-f16 Schraudolph:
//   per score-pair: cvt_pkrtz -> v_pk_max_f16(16) -> v_pk_mad_u16(*16+0x43D4)
//   -- the result IS the PV B-word.
// PV MFMA 32x32x16_f16: D layout (col=lane&31=q,
// row=(reg&3)+8*(reg>>2)+4*hi=src) => packed weights are the PV B-operand
// when flow values are stored permuted {0-3,8-11 | 4-7,12-15} per
// 16-source group (fpk). acc regs 0-3 on lanes<32 = (nx,ny,nz,den)/query.

#define N1S  8192
#define N2S  8192
#define BATCH 2
#define NS   (BATCH * N1S)       // 16384 sources
#define NQ   (BATCH * N2S)       // 16384 queries
#define GA   (NS + 128)          // srcA records + guard
#define NF   (NS/2 + 64)         // fpk records + guard
#define BLK  1024                // 16 waves; each wave: 512 sources = 16 tiles
#define QBQ  64                  // queries per block (2 cols of 32)
#define LOG2E 1.4426950408889634f
#define BIAS 30.0f               // s = BIAS + log2(w); s in [16, ~30.1]
#define ONEH 0x3C00u             // f16(1.0)
#define WADJ 0x43D4u             // 0x4400 base - 44 Schraudolph mid-corr

typedef __attribute__((ext_vector_type(2)))  __fp16         hp2;
typedef __attribute__((ext_vector_type(4)))  _Float16 f16x4;
typedef __attribute__((ext_vector_type(8)))  _Float16 f16x8;
typedef __attribute__((ext_vector_type(16))) float    f32x16;

__device__ __forceinline__ float read_scale(const void* p) {
    // resol_factor: 1-elem array; Python int -> int32, float -> fp32.
    int iv = *(const int*)p;
    if (iv > -(1 << 23) && iv < (1 << 23)) return (float)iv;
    return *(const float*)p;
}

__device__ __forceinline__ unsigned hb(float v) {        // f16 bits, RNE
    return (unsigned)__builtin_bit_cast(unsigned short, (_Float16)v);
}
__device__ __forceinline__ float h2f(unsigned b16) {     // f16 bits -> fp32
    return (float)__builtin_bit_cast(_Float16, (unsigned short)(b16 & 0xFFFFu));
}

// two Schraudolph-f16 weights from two f32 scores: one packed PV B-word.
// 3 VALU: v_cvt_pkrtz_f16_f32, v_pk_max_f16, v_pk_mad_u16 (bits*16 + WADJ
// per half, mod 2^16). mul/adj live in hoisted VGPRs (VOP3P: no literals).
__device__ __forceinline__ unsigned wpair(float a, float b,
                                          unsigned mul16, unsigned adj) {
    hp2 s = __builtin_amdgcn_cvt_pkrtz(a, b);            // v_cvt_pkrtz_f16_f32
    const hp2 cl = {(__fp16)16.0f, (__fp16)16.0f};
    s = __builtin_elementwise_max(s, cl);                // v_pk_max_f16
    unsigned u = __builtin_bit_cast(unsigned, s), r;
    asm("v_pk_mad_u16 %0, %1, %2, %3"
        : "=v"(r) : "v"(u), "v"(mul16), "v"(adj));
    return r;
}

// ---- k1: build srcA (score A-operand) and fpk (PV A-operand, f16) ----
__global__ __launch_bounds__(256) void pw2_pack(
    const float* __restrict__ xyz1, const float* __restrict__ flow1,
    const void* __restrict__ resol, uint4* __restrict__ srcA,
    uint4* __restrict__ fpk)
{
    const int i = blockIdx.x * 256 + threadIdx.x;
    const float scale = read_scale(resol);
    const float c1 = LOG2E / (scale * scale);

    if (i < NS) {
        const int b = i >> 13, m = i & (N1S - 1);
        const float* x1b = xyz1  + b * 3 * N1S;
        const float* f1b = flow1 + b * 3 * N1S;
        float fx = f1b[0*N1S+m], fy = f1b[1*N1S+m], fz = f1b[2*N1S+m];
        float yx = x1b[0*N1S+m]+fx, yy = x1b[1*N1S+m]+fy, yz = x1b[2*N1S+m]+fz;
        float wq = -c1 * (yx*yx + yy*yy + yz*yz);   // fp32-exact, f16 hi/lo
        unsigned hx = hb(yx), hy = hb(yy), hz = hb(yz);
        unsigned wh = hb(wq), wl = hb(wq - h2f(wh));
        uint4 A;                      // halves: lanes<32 read .xy, >=32 .zw
        A.x = hx | (hy << 16);        // k0,k1 = yx,yy
        A.y = hz | (ONEH << 16);      // k2,k3 = yz,1
        A.z = ONEH | (wh << 16);      // k4,k5 = 1,wh
        A.w = wl;                     // k6,k7 = wl,0
        srcA[i] = A;
    }

    if (i < NS / 2) {
        // fpk record i: group g of 16 sources, half h, component c (c=3 -> 1).
        // k-order permutation per group: h=0 -> {0,1,2,3,8,9,10,11},
        //                                h=1 -> {4,5,6,7,12,13,14,15}.
        const int g = i >> 3, h = (i >> 2) & 1, c = i & 3;
        const int b = g >> 9, m0 = (g & 511) * 16;
        const float* f1c = flow1 + b * 3 * N1S + (c < 3 ? c : 0) * N1S;
        const int base = h * 4;
        unsigned e[8];
#pragma unroll
        for (int j = 0; j < 8; ++j) {
            int s = m0 + base + (j & 3) + (j >> 2) * 8;
            e[j] = (c == 3) ? ONEH : hb(f1c[s]);
        }
        uint4 F;
        F.x = e[0] | (e[1] << 16);
        F.y = e[2] | (e[3] << 16);
        F.z = e[4] | (e[5] << 16);
        F.w = e[6] | (e[7] << 16);
        fpk[i] = F;
    }
}

// ---- k2: MFMA main kernel, 64 queries/block, 16 waves ----
__global__ __launch_bounds__(BLK, 4) void pw2_main(
    const uint4* __restrict__ srcA, const uint4* __restrict__ fpk,
    const float* __restrict__ xyz2, const void* __restrict__ resol,
    float* __restrict__ out)
{
    __shared__ float4 red[16][QBQ];   // [wave][query] partial (nx,ny,nz,den)

    const int t  = threadIdx.x;
    const int w  = t >> 6, l = t & 63, lq = l & 31, hi = l >> 5;
    const int qblk  = blockIdx.x * QBQ;
    const int b     = qblk >> 13;
    const int nbase = qblk & (N2S - 1);

    const float scale = read_scale(resol);
    const float c1 = LOG2E / (scale * scale), twoC = 2.0f * c1;
    const float* x2b = xyz2 + b * 3 * N2S;

    // hoisted VOP3P constants for wpair (no literals allowed in VOP3P)
    const unsigned mul16 = 0x00100010u;
    const unsigned adj   = (WADJ << 16) | WADJ;

    // ---- per-lane query constants for 2 columns -> B frags ----
    uint2 bw0, bw1;
#pragma unroll
    for (int cc = 0; cc < 2; ++cc) {
        const int n0 = nbase + 32 * cc + lq;
        const float qx = x2b[n0], qy = x2b[N2S+n0], qz = x2b[2*N2S+n0];
        const unsigned Xh = hb(twoC*qx), Yh = hb(twoC*qy), Zh = hb(twoC*qz);
        const float qc = BIAS - c1 * (qx*qx + qy*qy + qz*qz);
        const unsigned Qh = hb(qc), Ql = hb(qc - h2f(Qh));
        uint2 bwv;
        bwv.x = hi ? (Ql | (ONEH << 16)) : (Xh | (Yh << 16)); // k4,k5 | k0,k1
        bwv.y = hi ? ONEH                : (Zh | (Qh << 16)); // k6,k7 | k2,k3
        if (cc == 0) bw0 = bwv; else bw1 = bwv;
    }
    const f16x4 Bf0 = __builtin_bit_cast(f16x4, bw0);
    const f16x4 Bf1 = __builtin_bit_cast(f16x4, bw1);

    f32x16 acc0, acc1, zc;
#pragma unroll
    for (int k = 0; k < 16; ++k) { acc0[k] = 0.f; acc1[k] = 0.f; zc[k] = 0.f; }

    // ---- source loop: 16 tiles x 32 sources; depth-1 guarded prefetch ----
    const uint2* a2 = (const uint2*)srcA;   // lane reads its 8B half-record
    int ia = (b * N1S + w * 512 + lq) * 2 + hi;
    int ir = ((b * N1S + w * 512) >> 4) * 8 + hi * 4 + (l & 3);

    uint2 s0 = a2[ia];
    uint4 f0 = fpk[ir], f1 = fpk[ir + 8];

#pragma unroll 2
    for (int tt = 0; tt < 16; ++tt) {
        // prefetch next tile (guard regions: always legal)
        const uint2 s0n = a2[ia + 64];
        const uint4 f0n = fpk[ir + 16];
        const uint4 f1n = fpk[ir + 24];

        const f32x16 d0 = __builtin_amdgcn_mfma_f32_32x32x8f16(
            __builtin_bit_cast(f16x4, s0), Bf0, zc, 0, 0, 0);
        const f32x16 d1 = __builtin_amdgcn_mfma_f32_32x32x8f16(
            __builtin_bit_cast(f16x4, s0), Bf1, zc, 0, 0, 0);

        uint4 p;
        p.x = wpair(d0[0],  d0[1],  mul16, adj);
        p.y = wpair(d0[2],  d0[3],  mul16, adj);
        p.z = wpair(d0[4],  d0[5],  mul16, adj);
        p.w = wpair(d0[6],  d0[7],  mul16, adj);
        acc0 = __builtin_amdgcn_mfma_f32_32x32x16_f16(
            __builtin_bit_cast(f16x8, f0), __builtin_bit_cast(f16x8, p),
            acc0, 0, 0, 0);
        p.x = wpair(d0[8],  d0[9],  mul16, adj);
        p.y = wpair(d0[10], d0[11], mul16, adj);
        p.z = wpair(d0[12], d0[13], mul16, adj);
        p.w = wpair(d0[14], d0[15], mul16, adj);
        acc0 = __builtin_amdgcn_mfma_f32_32x32x16_f16(
            __builtin_bit_cast(f16x8, f1), __builtin_bit_cast(f16x8, p),
            acc0, 0, 0, 0);

        p.x = wpair(d1[0],  d1[1],  mul16, adj);
        p.y = wpair(d1[2],  d1[3],  mul16, adj);
        p.z = wpair(d1[4],  d1[5],  mul16, adj);
        p.w = wpair(d1[6],  d1[7],  mul16, adj);
        acc1 = __builtin_amdgcn_mfma_f32_32x32x16_f16(
            __builtin_bit_cast(f16x8, f0), __builtin_bit_cast(f16x8, p),
            acc1, 0, 0, 0);
        p.x = wpair(d1[8],  d1[9],  mul16, adj);
        p.y = wpair(d1[10], d1[11], mul16, adj);
        p.z = wpair(d1[12], d1[13], mul16, adj);
        p.w = wpair(d1[14], d1[15], mul16, adj);
        acc1 = __builtin_amdgcn_mfma_f32_32x32x16_f16(
            __builtin_bit_cast(f16x8, f1), __builtin_bit_cast(f16x8, p),
            acc1, 0, 0, 0);

        s0 = s0n; f0 = f0n; f1 = f1n;
        ia += 64; ir += 16;
    }

    // ---- cross-wave reduce + normalize + write ----
    if (hi == 0) {
        red[w][lq]      = make_float4(acc0[0], acc0[1], acc0[2], acc0[3]);
        red[w][32 + lq] = make_float4(acc1[0], acc1[1], acc1[2], acc1[3]);
    }
    __syncthreads();
    if (t < QBQ) {
        float nx = 0.f, ny = 0.f, nz = 0.f, dn = 0.f;
#pragma unroll
        for (int ww = 0; ww < 16; ++ww) {
            float4 r = red[ww][t];
            nx += r.x; ny += r.y; nz += r.z; dn += r.w;
        }
        const float inv = 1.0f / dn;
        const int nq = nbase + t;
        out[b*3*N2S + 0*N2S + nq] = x2b[0*N2S+nq] - nx * inv;
        out[b*3*N2S + 1*N2S + nq] = x2b[1*N2S+nq] - ny * inv;
        out[b*3*N2S + 2*N2S + nq] = x2b[2*N2S+nq] - nz * inv;
    }
}

extern "C" void kernel_launch(void* const* d_in, const int* in_sizes, int n_in,
                              void* d_out, int out_size, void* d_ws, size_t ws_size,
                              hipStream_t stream) {
    const float* xyz1  = (const float*)d_in[0];
    const float* xyz2  = (const float*)d_in[1];
    const float* flow1 = (const float*)d_in[2];
    const void*  resol = d_in[3];
    float* out = (float*)d_out;

    uint4* srcA = (uint4*)d_ws;        // GA records
    uint4* fpk  = srcA + GA;           // NF records; total ~400 KB

    pw2_pack<<<NS / 256, 256, 0, stream>>>(xyz1, flow1, resol, srcA, fpk);
    pw2_main<<<NQ / QBQ, BLK, 0, stream>>>(srcA, fpk, xyz2, resol, out);
}